// Round 12
// baseline (175.237 us; speedup 1.0000x reference)
//
#include <hip/hip_runtime.h>

#define BLOCK 512   // 8 waves
#define GRID  512   // 2 blocks/CU resident (VGPR tier), grid = exact multiple

typedef __attribute__((ext_vector_type(8))) short short8;   // 8 x bf16
typedef __attribute__((ext_vector_type(4))) float f32x4;    // MFMA C/D frag

#define TWOLOG2E  2.8853900817779268f   // 2*log2(e), folded into g/beta
#define NLOG2E   -1.4426950408889634f   // -log2(e), folded into W4/b4
#define HP 66   // h-tile pitch in bf16 (33 dwords): measured 0 bank conflicts (R8)

__device__ __forceinline__ unsigned short f2bf(float f) {
    unsigned u = __builtin_bit_cast(unsigned, f);
    u += 0x7FFFu + ((u >> 16) & 1u);
    return (unsigned short)(u >> 16);
}

__device__ __forceinline__ unsigned pkbf(float lo, float hi) {
    unsigned r;
    asm("v_cvt_pk_bf16_f32 %0, %1, %2" : "=v"(r) : "v"(lo), "v"(hi));
    return r;
}

// tanh via pre-scaled z = v*g' + bt' (g' = 2log2e*g): 1 - 2*rcp(1+exp2(z))
__device__ __forceinline__ float tanh_z(float z) {
    float e = __builtin_amdgcn_exp2f(z);
    return fmaf(-2.0f, __builtin_amdgcn_rcpf(1.0f + e), 1.0f);
}

// LayerNorm + tanh, transposed layout: lane holds edge `cl`, h-cols m*16+kg*4+i.
// Stats reduce across the 4 kg groups via convergent __shfl_xor (permlane asm
// regressed twice: R10 regalloc coalesce, R11 suspected non-convergent sink).
#define LN_T(PB, PG, PT, A)                                                   \
    {                                                                         \
        float s = 0.f, q = 0.f;                                               \
        _Pragma("unroll")                                                     \
        for (int m = 0; m < 4; ++m) {                                         \
            const float4 pb = *reinterpret_cast<const float4*>(               \
                plds + (PB) * 64 + m * 16 + kg4);                             \
            A[m][0] += pb.x; A[m][1] += pb.y;                                 \
            A[m][2] += pb.z; A[m][3] += pb.w;                                 \
            s += (A[m][0] + A[m][1]) + (A[m][2] + A[m][3]);                   \
            q = fmaf(A[m][0], A[m][0], q); q = fmaf(A[m][1], A[m][1], q);     \
            q = fmaf(A[m][2], A[m][2], q); q = fmaf(A[m][3], A[m][3], q);     \
        }                                                                     \
        s += __shfl_xor(s, 16); s += __shfl_xor(s, 32);                       \
        q += __shfl_xor(q, 16); q += __shfl_xor(q, 32);                       \
        const float mu = s * 0.015625f;                                       \
        float var = fmaf(q, 0.015625f, -mu * mu);                             \
        var = fmaxf(var, 0.0f);                                               \
        const float rs = __builtin_amdgcn_rsqf(var + 1e-5f);                  \
        const float mrs = mu * rs;                                            \
        _Pragma("unroll")                                                     \
        for (int m = 0; m < 4; ++m) {                                         \
            const float4 pg = *reinterpret_cast<const float4*>(               \
                plds + (PG) * 64 + m * 16 + kg4);                             \
            const float4 pt = *reinterpret_cast<const float4*>(               \
                plds + (PT) * 64 + m * 16 + kg4);                             \
            A[m][0] = tanh_z(fmaf(fmaf(A[m][0], rs, -mrs), pg.x, pt.x));      \
            A[m][1] = tanh_z(fmaf(fmaf(A[m][1], rs, -mrs), pg.y, pt.y));      \
            A[m][2] = tanh_z(fmaf(fmaf(A[m][2], rs, -mrs), pg.z, pt.z));      \
            A[m][3] = tanh_z(fmaf(fmaf(A[m][3], rs, -mrs), pg.w, pt.w));      \
        }                                                                     \
    }

#define H_STORE_T(A)                                                          \
    _Pragma("unroll")                                                         \
    for (int m = 0; m < 4; ++m) {                                             \
        uint2 u2;                                                             \
        u2.x = pkbf(A[m][0], A[m][1]);                                        \
        u2.y = pkbf(A[m][2], A[m][3]);                                        \
        *reinterpret_cast<uint2*>(hwv + cl * HP + m * 16 + kg4) = u2;         \
    }

// issue the 8 x-gather loads (f32 path) or 4 bf16 loads for a tile
#define GATHER(NS, NE)                                                        \
    _Pragma("unroll")                                                         \
    for (int kb = 0; kb < 4; ++kb) {                                          \
        const unsigned off = (unsigned)(kb < 2 ? (NS) : (NE)) * 64u           \
                           + (unsigned)((kb & 1) * 32 + kg * 8);              \
        if constexpr (PREBF) {                                                \
            xa[kb] = *reinterpret_cast<const short8*>(xb + off);              \
        } else {                                                              \
            u[2 * kb]     = *reinterpret_cast<const float4*>(xf + off);       \
            u[2 * kb + 1] = *reinterpret_cast<const float4*>(xf + off + 4);   \
        }                                                                     \
    }

#define LDIDX(T, A_, B_)                                                      \
    {                                                                         \
        const int tc_ = min((T), ntiles - 1);                                 \
        const int er_ = min((tc_ << 4) + cl, E - 1);                          \
        A_ = ei[er_]; B_ = ei[E + er_];                                       \
    }

template<bool PREBF>
__global__ __launch_bounds__(BLOCK) void edge_mlp_t(
    const void* __restrict__ xsrc, const int* __restrict__ ei,
    const float* __restrict__ W1, const float* __restrict__ b1,
    const float* __restrict__ g1, const float* __restrict__ bt1,
    const float* __restrict__ W2, const float* __restrict__ b2,
    const float* __restrict__ g2, const float* __restrict__ bt2,
    const float* __restrict__ W3, const float* __restrict__ b3,
    const float* __restrict__ g3, const float* __restrict__ bt3,
    const float* __restrict__ W4, const float* __restrict__ b4,
    float* __restrict__ out, int E)
{
    __shared__ unsigned short wlds[32 * 512];          // 32 KiB W^T frags
    __shared__ unsigned short hlds[8 * 16 * HP];       // per-wave [16 edge][HP] bf16
    __shared__ float plds[10 * 64];                    // b,g',bt' x3 + W4'

    const int tid  = threadIdx.x;
    const int widx = tid >> 6;
    const int lane = tid & 63;
    const int kg   = lane >> 4;   // 0..3
    const int cl   = lane & 15;   // 0..15 = edge within tile
    const int kg4  = kg * 4;

    for (int fi = widx; fi < 32; fi += 8) {
        const float* Wsrc; int m, kb;
        if (fi < 16) { Wsrc = W1; m = fi >> 2; kb = fi & 3; }
        else { int f = fi - 16; Wsrc = (f < 8) ? W2 : W3; f &= 7; m = f >> 1; kb = f & 1; }
        const float* src = Wsrc + (kb * 32 + kg * 8) * 64 + m * 16 + cl;
        short8 pk8;
        #pragma unroll
        for (int j = 0; j < 8; ++j) pk8[j] = (short)f2bf(src[j * 64]);
        *reinterpret_cast<short8*>(&wlds[fi * 512 + lane * 8]) = pk8;
    }
    // params -> LDS with constant folding: g,bt scaled by 2log2e; W4 by -log2e
    for (int i = tid; i < 640; i += BLOCK) {
        const int p = i >> 6, c = i & 63;
        const float* sp; float sc;
        switch (p) {
            case 0: sp = b1;  sc = 1.0f;     break;
            case 1: sp = g1;  sc = TWOLOG2E; break;
            case 2: sp = bt1; sc = TWOLOG2E; break;
            case 3: sp = b2;  sc = 1.0f;     break;
            case 4: sp = g2;  sc = TWOLOG2E; break;
            case 5: sp = bt2; sc = TWOLOG2E; break;
            case 6: sp = b3;  sc = 1.0f;     break;
            case 7: sp = g3;  sc = TWOLOG2E; break;
            case 8: sp = bt3; sc = TWOLOG2E; break;
            default: sp = W4; sc = NLOG2E;   break;
        }
        plds[i] = sp[c] * sc;
    }
    const float b4s = b4[0] * NLOG2E;
    __syncthreads();

    const unsigned short* xb = (const unsigned short*)xsrc;
    const float*          xf = (const float*)xsrc;
    unsigned short* hwv = hlds + widx * (16 * HP);

    const int ntiles = (E + 15) >> 4;
    const int NW = (int)gridDim.x * 8;

    int t = (int)blockIdx.x * 8 + widx;

    // ---- 2-deep pipeline: x data of tile t, indices of tile t+NW in flight ----
    float4 u[8];
    short8 xa[4];
    int ns1, ne1;
    {
        int ns0, ne0;
        LDIDX(t, ns0, ne0);
        GATHER(ns0, ne0);
        LDIDX(t + NW, ns1, ne1);
    }

    for (; t < ntiles; t += NW) {
        // ---- consume this tile's x (in flight since last iteration) ----
        short8 af[4];
        if constexpr (PREBF) {
            #pragma unroll
            for (int kb = 0; kb < 4; ++kb) af[kb] = xa[kb];
        } else {
            #pragma unroll
            for (int kb = 0; kb < 4; ++kb) {
                uint4 tp_;
                tp_.x = pkbf(u[2 * kb].x,     u[2 * kb].y);
                tp_.y = pkbf(u[2 * kb].z,     u[2 * kb].w);
                tp_.z = pkbf(u[2 * kb + 1].x, u[2 * kb + 1].y);
                tp_.w = pkbf(u[2 * kb + 1].z, u[2 * kb + 1].w);
                af[kb] = __builtin_bit_cast(short8, tp_);
            }
        }

        // ---- immediately re-issue: next tile's x + next-next indices ----
        GATHER(ns1, ne1);
        LDIDX(t + 2 * NW, ns1, ne1);

        // ---------- Layer 1 ----------
        f32x4 acc[4] = {{0,0,0,0},{0,0,0,0},{0,0,0,0},{0,0,0,0}};
        #pragma unroll
        for (int kb = 0; kb < 4; ++kb) {
            #pragma unroll
            for (int m = 0; m < 4; ++m) {
                const short8 wf = *reinterpret_cast<const short8*>(
                    &wlds[(m * 4 + kb) * 512 + lane * 8]);
                acc[m] = __builtin_amdgcn_mfma_f32_16x16x32_bf16(wf, af[kb], acc[m], 0, 0, 0);
            }
        }
        LN_T(0, 1, 2, acc);
        H_STORE_T(acc);

        // ---------- Layer 2 ----------
        f32x4 acc2[4] = {{0,0,0,0},{0,0,0,0},{0,0,0,0},{0,0,0,0}};
        #pragma unroll
        for (int kb = 0; kb < 2; ++kb) {
            const short8 hf = *reinterpret_cast<const short8*>(
                hwv + cl * HP + kb * 32 + kg * 8);
            #pragma unroll
            for (int m = 0; m < 4; ++m) {
                const short8 wf = *reinterpret_cast<const short8*>(
                    &wlds[(16 + m * 2 + kb) * 512 + lane * 8]);
                acc2[m] = __builtin_amdgcn_mfma_f32_16x16x32_bf16(wf, hf, acc2[m], 0, 0, 0);
            }
        }
        LN_T(3, 4, 5, acc2);
        H_STORE_T(acc2);

        // ---------- Layer 3 ----------
        f32x4 acc3[4] = {{0,0,0,0},{0,0,0,0},{0,0,0,0},{0,0,0,0}};
        #pragma unroll
        for (int kb = 0; kb < 2; ++kb) {
            const short8 hf = *reinterpret_cast<const short8*>(
                hwv + cl * HP + kb * 32 + kg * 8);
            #pragma unroll
            for (int m = 0; m < 4; ++m) {
                const short8 wf = *reinterpret_cast<const short8*>(
                    &wlds[(24 + m * 2 + kb) * 512 + lane * 8]);
                acc3[m] = __builtin_amdgcn_mfma_f32_16x16x32_bf16(wf, hf, acc3[m], 0, 0, 0);
            }
        }
        LN_T(6, 7, 8, acc3);

        // ---------- Layer 4: in-lane dot (W4 pre-scaled) + sigmoid ----------
        float p = 0.f;
        #pragma unroll
        for (int m = 0; m < 4; ++m) {
            const float4 w4 = *reinterpret_cast<const float4*>(
                plds + 9 * 64 + m * 16 + kg4);
            p = fmaf(acc3[m][0], w4.x, p); p = fmaf(acc3[m][1], w4.y, p);
            p = fmaf(acc3[m][2], w4.z, p); p = fmaf(acc3[m][3], w4.w, p);
        }
        p += __shfl_xor(p, 16); p += __shfl_xor(p, 32);
        if (kg == 0) {
            const int e = (t << 4) + cl;
            if (e < E) {
                // p already = -log2(e) * h.W4; b4s = -log2(e)*b4
                out[e] = __builtin_amdgcn_rcpf(
                    1.0f + __builtin_amdgcn_exp2f(p + b4s));
            }
        }
    }
}

__global__ __launch_bounds__(256) void cvt_x_bf16(const float* __restrict__ x,
                                                  unsigned short* __restrict__ xbf,
                                                  int n) {
    const int i = (blockIdx.x * 256 + threadIdx.x) * 8;
    if (i >= n) return;
    const float4 u0 = *reinterpret_cast<const float4*>(x + i);
    const float4 u1 = *reinterpret_cast<const float4*>(x + i + 4);
    uint4 t;
    t.x = pkbf(u0.x, u0.y); t.y = pkbf(u0.z, u0.w);
    t.z = pkbf(u1.x, u1.y); t.w = pkbf(u1.z, u1.w);
    *reinterpret_cast<uint4*>(xbf + i) = t;
}

extern "C" void kernel_launch(void* const* d_in, const int* in_sizes, int n_in,
                              void* d_out, int out_size, void* d_ws, size_t ws_size,
                              hipStream_t stream) {
    const float* x   = (const float*)d_in[0];
    const int*   ei  = (const int*)  d_in[1];
    const float* W1  = (const float*)d_in[2];
    const float* b1  = (const float*)d_in[3];
    const float* g1  = (const float*)d_in[4];
    const float* bt1 = (const float*)d_in[5];
    const float* W2  = (const float*)d_in[6];
    const float* b2  = (const float*)d_in[7];
    const float* g2  = (const float*)d_in[8];
    const float* bt2 = (const float*)d_in[9];
    const float* W3  = (const float*)d_in[10];
    const float* b3  = (const float*)d_in[11];
    const float* g3  = (const float*)d_in[12];
    const float* bt3 = (const float*)d_in[13];
    const float* W4  = (const float*)d_in[14];
    const float* b4  = (const float*)d_in[15];
    float* out = (float*)d_out;

    const int E  = in_sizes[1] / 2;
    const int nX = in_sizes[0];                 // n_nodes * 64

    const bool prebf = (ws_size >= (size_t)nX * 2);

    if (prebf) {
        unsigned short* xbf = (unsigned short*)d_ws;
        const int grid_c = (nX / 8 + 255) / 256;
        hipLaunchKernelGGL(cvt_x_bf16, dim3(grid_c), dim3(256), 0, stream, x, xbf, nX);
        hipLaunchKernelGGL((edge_mlp_t<true>), dim3(GRID), dim3(BLOCK), 0, stream,
                           (const void*)xbf, ei, W1, b1, g1, bt1, W2, b2, g2, bt2,
                           W3, b3, g3, bt3, W4, b4, out, E);
    } else {
        hipLaunchKernelGGL((edge_mlp_t<false>), dim3(GRID), dim3(BLOCK), 0, stream,
                           (const void*)x, ei, W1, b1, g1, bt1, W2, b2, g2, bt2,
                           W3, b3, g3, bt3, W4, b4, out, E);
    }
}

// Round 13
// 119.187 us; speedup vs baseline: 1.4703x; 1.4703x over previous
//
#include <hip/hip_runtime.h>

#define BLOCK 512   // 8 waves
#define GRID  512   // 2 blocks/CU resident (VGPR tier)

typedef __attribute__((ext_vector_type(8))) short short8;   // 8 x bf16
typedef __attribute__((ext_vector_type(4))) float f32x4;    // MFMA C/D frag

#define TWOLOG2E  2.8853900817779268f
#define NLOG2E   -1.4426950408889634f
// h-pitch RULES (R12 lesson): 2*HP must be mult of 16 (alignment of ds_read_b128);
// HP=66 (132B) split every ds op -> 117->179us. HP=72: aligned, reads 2-way (free).
#define HP 72

__device__ __forceinline__ unsigned short f2bf(float f) {
    unsigned u = __builtin_bit_cast(unsigned, f);
    u += 0x7FFFu + ((u >> 16) & 1u);
    return (unsigned short)(u >> 16);
}

__device__ __forceinline__ unsigned pkbf(float lo, float hi) {
    unsigned r;
    asm("v_cvt_pk_bf16_f32 %0, %1, %2" : "=v"(r) : "v"(lo), "v"(hi));
    return r;
}

__device__ __forceinline__ float tanh_z(float z) {
    float e = __builtin_amdgcn_exp2f(z);
    return fmaf(-2.0f, __builtin_amdgcn_rcpf(1.0f + e), 1.0f);
}

#define LN_T(PB, PG, PT, A)                                                   \
    {                                                                         \
        float s_ = 0.f, q_ = 0.f;                                             \
        _Pragma("unroll")                                                     \
        for (int m = 0; m < 4; ++m) {                                         \
            const float4 pb = *reinterpret_cast<const float4*>(               \
                plds + (PB) * 64 + m * 16 + kg4);                             \
            A[m][0] += pb.x; A[m][1] += pb.y;                                 \
            A[m][2] += pb.z; A[m][3] += pb.w;                                 \
            s_ += (A[m][0] + A[m][1]) + (A[m][2] + A[m][3]);                  \
            q_ = fmaf(A[m][0], A[m][0], q_); q_ = fmaf(A[m][1], A[m][1], q_); \
            q_ = fmaf(A[m][2], A[m][2], q_); q_ = fmaf(A[m][3], A[m][3], q_); \
        }                                                                     \
        s_ += __shfl_xor(s_, 16); s_ += __shfl_xor(s_, 32);                   \
        q_ += __shfl_xor(q_, 16); q_ += __shfl_xor(q_, 32);                   \
        const float mu = s_ * 0.015625f;                                      \
        float var = fmaf(q_, 0.015625f, -mu * mu);                            \
        var = fmaxf(var, 0.0f);                                               \
        const float rs = __builtin_amdgcn_rsqf(var + 1e-5f);                  \
        const float mrs = mu * rs;                                            \
        _Pragma("unroll")                                                     \
        for (int m = 0; m < 4; ++m) {                                         \
            const float4 pg = *reinterpret_cast<const float4*>(               \
                plds + (PG) * 64 + m * 16 + kg4);                             \
            const float4 pt = *reinterpret_cast<const float4*>(               \
                plds + (PT) * 64 + m * 16 + kg4);                             \
            A[m][0] = tanh_z(fmaf(fmaf(A[m][0], rs, -mrs), pg.x, pt.x));      \
            A[m][1] = tanh_z(fmaf(fmaf(A[m][1], rs, -mrs), pg.y, pt.y));      \
            A[m][2] = tanh_z(fmaf(fmaf(A[m][2], rs, -mrs), pg.z, pt.z));      \
            A[m][3] = tanh_z(fmaf(fmaf(A[m][3], rs, -mrs), pg.w, pt.w));      \
        }                                                                     \
    }

#define H_STORE(A, HW)                                                        \
    _Pragma("unroll")                                                         \
    for (int m = 0; m < 4; ++m) {                                             \
        uint2 u2;                                                             \
        u2.x = pkbf(A[m][0], A[m][1]);                                        \
        u2.y = pkbf(A[m][2], A[m][3]);                                        \
        *reinterpret_cast<uint2*>((HW) + cl * HP + m * 16 + kg4) = u2;        \
    }

#define GATHER_F(U, NS, NE)                                                   \
    _Pragma("unroll")                                                         \
    for (int kb = 0; kb < 4; ++kb) {                                          \
        const unsigned off = (unsigned)(kb < 2 ? (NS) : (NE)) * 64u           \
                           + (unsigned)((kb & 1) * 32 + kg * 8);              \
        U[2 * kb]     = *reinterpret_cast<const float4*>(xf + off);           \
        U[2 * kb + 1] = *reinterpret_cast<const float4*>(xf + off + 4);       \
    }

#define GATHER_B(XA, NS, NE)                                                  \
    _Pragma("unroll")                                                         \
    for (int kb = 0; kb < 4; ++kb) {                                          \
        const unsigned off = (unsigned)(kb < 2 ? (NS) : (NE)) * 64u           \
                           + (unsigned)((kb & 1) * 32 + kg * 8);              \
        XA[kb] = *reinterpret_cast<const short8*>(xb + off);                  \
    }

#define CVT8(U, AF)                                                           \
    _Pragma("unroll")                                                         \
    for (int kb = 0; kb < 4; ++kb) {                                          \
        uint4 tp_;                                                            \
        tp_.x = pkbf(U[2 * kb].x,     U[2 * kb].y);                           \
        tp_.y = pkbf(U[2 * kb].z,     U[2 * kb].w);                           \
        tp_.z = pkbf(U[2 * kb + 1].x, U[2 * kb + 1].y);                       \
        tp_.w = pkbf(U[2 * kb + 1].z, U[2 * kb + 1].w);                       \
        AF[kb] = __builtin_bit_cast(short8, tp_);                             \
    }

#define L1_MFMA(AF, ACC)                                                      \
    _Pragma("unroll")                                                         \
    for (int kb = 0; kb < 4; ++kb) {                                          \
        _Pragma("unroll")                                                     \
        for (int m = 0; m < 4; ++m) {                                         \
            const short8 wf = *reinterpret_cast<const short8*>(               \
                &wlds[(m * 4 + kb) * 512 + lane * 8]);                        \
            ACC[m] = __builtin_amdgcn_mfma_f32_16x16x32_bf16(wf, AF[kb], ACC[m], 0, 0, 0); \
        }                                                                     \
    }

#define L23_MFMA(HW, ACC, BASE)                                               \
    _Pragma("unroll")                                                         \
    for (int kb = 0; kb < 2; ++kb) {                                          \
        const short8 hf = *reinterpret_cast<const short8*>(                   \
            (HW) + cl * HP + kb * 32 + kg * 8);                               \
        _Pragma("unroll")                                                     \
        for (int m = 0; m < 4; ++m) {                                         \
            const short8 wf = *reinterpret_cast<const short8*>(               \
                &wlds[((BASE) + m * 2 + kb) * 512 + lane * 8]);               \
            ACC[m] = __builtin_amdgcn_mfma_f32_16x16x32_bf16(wf, hf, ACC[m], 0, 0, 0); \
        }                                                                     \
    }

#define L4_OUT(ACC3, T)                                                       \
    {                                                                         \
        float p = 0.f;                                                        \
        _Pragma("unroll")                                                     \
        for (int m = 0; m < 4; ++m) {                                         \
            const float4 w4 = *reinterpret_cast<const float4*>(               \
                plds + 9 * 64 + m * 16 + kg4);                                \
            p = fmaf(ACC3[m][0], w4.x, p); p = fmaf(ACC3[m][1], w4.y, p);     \
            p = fmaf(ACC3[m][2], w4.z, p); p = fmaf(ACC3[m][3], w4.w, p);     \
        }                                                                     \
        p += __shfl_xor(p, 16); p += __shfl_xor(p, 32);                       \
        if (kg == 0) {                                                        \
            const int e = ((T) << 4) + cl;                                    \
            if (e < E) out[e] = __builtin_amdgcn_rcpf(                        \
                1.0f + __builtin_amdgcn_exp2f(p + b4s));                      \
        }                                                                     \
    }

#define LDIDX(T, A_, B_)                                                      \
    {                                                                         \
        const int tc_ = min((T), ntiles - 1);                                 \
        const int er_ = min((tc_ << 4) + cl, E - 1);                          \
        A_ = ei[er_]; B_ = ei[E + er_];                                       \
    }

template<bool PREBF>
__global__ __launch_bounds__(BLOCK) void edge_mlp_t(
    const void* __restrict__ xsrc, const int* __restrict__ ei,
    const float* __restrict__ W1, const float* __restrict__ b1,
    const float* __restrict__ g1, const float* __restrict__ bt1,
    const float* __restrict__ W2, const float* __restrict__ b2,
    const float* __restrict__ g2, const float* __restrict__ bt2,
    const float* __restrict__ W3, const float* __restrict__ b3,
    const float* __restrict__ g3, const float* __restrict__ bt3,
    const float* __restrict__ W4, const float* __restrict__ b4,
    float* __restrict__ out, int E)
{
    __shared__ unsigned short wlds[32 * 512];            // 32 KiB W^T frags
    __shared__ unsigned short hlds[8 * 2 * 16 * HP];     // 2 h-tiles per wave
    __shared__ float plds[10 * 64];

    const int tid  = threadIdx.x;
    const int widx = tid >> 6;
    const int lane = tid & 63;
    const int kg   = lane >> 4;
    const int cl   = lane & 15;
    const int kg4  = kg * 4;

    for (int fi = widx; fi < 32; fi += 8) {
        const float* Wsrc; int m, kb;
        if (fi < 16) { Wsrc = W1; m = fi >> 2; kb = fi & 3; }
        else { int f = fi - 16; Wsrc = (f < 8) ? W2 : W3; f &= 7; m = f >> 1; kb = f & 1; }
        const float* src = Wsrc + (kb * 32 + kg * 8) * 64 + m * 16 + cl;
        short8 pk8;
        #pragma unroll
        for (int j = 0; j < 8; ++j) pk8[j] = (short)f2bf(src[j * 64]);
        *reinterpret_cast<short8*>(&wlds[fi * 512 + lane * 8]) = pk8;
    }
    for (int i = tid; i < 640; i += BLOCK) {
        const int p = i >> 6, c = i & 63;
        const float* sp; float sc;
        switch (p) {
            case 0: sp = b1;  sc = 1.0f;     break;
            case 1: sp = g1;  sc = TWOLOG2E; break;
            case 2: sp = bt1; sc = TWOLOG2E; break;
            case 3: sp = b2;  sc = 1.0f;     break;
            case 4: sp = g2;  sc = TWOLOG2E; break;
            case 5: sp = bt2; sc = TWOLOG2E; break;
            case 6: sp = b3;  sc = 1.0f;     break;
            case 7: sp = g3;  sc = TWOLOG2E; break;
            case 8: sp = bt3; sc = TWOLOG2E; break;
            default: sp = W4; sc = NLOG2E;   break;
        }
        plds[i] = sp[c] * sc;
    }
    const float b4s = b4[0] * NLOG2E;
    __syncthreads();

    const unsigned short* xb = (const unsigned short*)xsrc;
    const float*          xf = (const float*)xsrc;
    unsigned short* hwvA = hlds + widx * (2 * 16 * HP);
    unsigned short* hwvB = hwvA + 16 * HP;

    const int ntiles = (E + 15) >> 4;
    const int NW = (int)gridDim.x * 8;

    int t = (int)blockIdx.x * 8 + widx;
    int nsA, neA, nsB, neB;
    LDIDX(t, nsA, neA);
    LDIDX(t + NW, nsB, neB);

    for (; t < ntiles; t += 2 * NW) {
        const int tb = t + NW;

        // ---- issue both tiles' gathers back-to-back (mutual latency overlap) ----
        float4 uA[8], uB[8];
        short8 afA[4], afB[4];
        if constexpr (PREBF) {
            GATHER_B(afA, nsA, neA);
            GATHER_B(afB, nsB, neB);
        } else {
            GATHER_F(uA, nsA, neA);
            GATHER_F(uB, nsB, neB);
        }
        // prefetch next pair's indices
        LDIDX(t + 2 * NW, nsA, neA);
        LDIDX(t + 3 * NW, nsB, neB);
        if constexpr (!PREBF) {
            CVT8(uA, afA);
            CVT8(uB, afB);
        }

        // ---- dual independent chains; compiler interleaves A and B ----
        f32x4 accA[4] = {{0,0,0,0},{0,0,0,0},{0,0,0,0},{0,0,0,0}};
        f32x4 accB[4] = {{0,0,0,0},{0,0,0,0},{0,0,0,0},{0,0,0,0}};
        L1_MFMA(afA, accA);
        L1_MFMA(afB, accB);
        LN_T(0, 1, 2, accA);
        LN_T(0, 1, 2, accB);
        H_STORE(accA, hwvA);
        H_STORE(accB, hwvB);

        f32x4 acc2A[4] = {{0,0,0,0},{0,0,0,0},{0,0,0,0},{0,0,0,0}};
        f32x4 acc2B[4] = {{0,0,0,0},{0,0,0,0},{0,0,0,0},{0,0,0,0}};
        L23_MFMA(hwvA, acc2A, 16);
        L23_MFMA(hwvB, acc2B, 16);
        LN_T(3, 4, 5, acc2A);
        LN_T(3, 4, 5, acc2B);
        H_STORE(acc2A, hwvA);
        H_STORE(acc2B, hwvB);

        f32x4 acc3A[4] = {{0,0,0,0},{0,0,0,0},{0,0,0,0},{0,0,0,0}};
        f32x4 acc3B[4] = {{0,0,0,0},{0,0,0,0},{0,0,0,0},{0,0,0,0}};
        L23_MFMA(hwvA, acc3A, 24);
        L23_MFMA(hwvB, acc3B, 24);
        LN_T(6, 7, 8, acc3A);
        LN_T(6, 7, 8, acc3B);

        L4_OUT(acc3A, t);
        L4_OUT(acc3B, tb);
    }
}

__global__ __launch_bounds__(256) void cvt_x_bf16(const float* __restrict__ x,
                                                  unsigned short* __restrict__ xbf,
                                                  int n) {
    const int i = (blockIdx.x * 256 + threadIdx.x) * 8;
    if (i >= n) return;
    const float4 u0 = *reinterpret_cast<const float4*>(x + i);
    const float4 u1 = *reinterpret_cast<const float4*>(x + i + 4);
    uint4 t;
    t.x = pkbf(u0.x, u0.y); t.y = pkbf(u0.z, u0.w);
    t.z = pkbf(u1.x, u1.y); t.w = pkbf(u1.z, u1.w);
    *reinterpret_cast<uint4*>(xbf + i) = t;
}

extern "C" void kernel_launch(void* const* d_in, const int* in_sizes, int n_in,
                              void* d_out, int out_size, void* d_ws, size_t ws_size,
                              hipStream_t stream) {
    const float* x   = (const float*)d_in[0];
    const int*   ei  = (const int*)  d_in[1];
    const float* W1  = (const float*)d_in[2];
    const float* b1  = (const float*)d_in[3];
    const float* g1  = (const float*)d_in[4];
    const float* bt1 = (const float*)d_in[5];
    const float* W2  = (const float*)d_in[6];
    const float* b2  = (const float*)d_in[7];
    const float* g2  = (const float*)d_in[8];
    const float* bt2 = (const float*)d_in[9];
    const float* W3  = (const float*)d_in[10];
    const float* b3  = (const float*)d_in[11];
    const float* g3  = (const float*)d_in[12];
    const float* bt3 = (const float*)d_in[13];
    const float* W4  = (const float*)d_in[14];
    const float* b4  = (const float*)d_in[15];
    float* out = (float*)d_out;

    const int E  = in_sizes[1] / 2;
    const int nX = in_sizes[0];

    const bool prebf = (ws_size >= (size_t)nX * 2);

    if (prebf) {
        unsigned short* xbf = (unsigned short*)d_ws;
        const int grid_c = (nX / 8 + 255) / 256;
        hipLaunchKernelGGL(cvt_x_bf16, dim3(grid_c), dim3(256), 0, stream, x, xbf, nX);
        hipLaunchKernelGGL((edge_mlp_t<true>), dim3(GRID), dim3(BLOCK), 0, stream,
                           (const void*)xbf, ei, W1, b1, g1, bt1, W2, b2, g2, bt2,
                           W3, b3, g3, bt3, W4, b4, out, E);
    } else {
        hipLaunchKernelGGL((edge_mlp_t<false>), dim3(GRID), dim3(BLOCK), 0, stream,
                           (const void*)x, ei, W1, b1, g1, bt1, W2, b2, g2, bt2,
                           W3, b3, g3, bt3, W4, b4, out, E);
    }
}